// Round 7
// baseline (427.109 us; speedup 1.0000x reference)
//
#include <hip/hip_runtime.h>
#include <hip/hip_bf16.h>

// Paged attention decode, GQA G=4, fp32. Fused flash-decoding split-K.
// B=16, H=32, KVH=8, D=128, MAX_CTX=4096.
// Block = (part, kvh-quad, b), 4 waves x 64. Each wave processes ONE token
// per iteration across the quad's 4 kv-heads (contiguous 2KB K + 2KB V).
// After writing its partial, the last-arriving block per (b,quad) (device
// atomic counter) performs the LSE merge inline -> no second kernel.

namespace {
constexpr int B_ = 16;
constexpr int H_ = 32;
constexpr int KVH_ = 8;
constexpr int D_ = 128;
constexpr int G_ = H_ / KVH_;            // 4
constexpr int MAX_CTX_ = 4096;
constexpr int PART_ = 64;
constexpr int NPART_ = MAX_CTX_ / PART_; // 64
constexpr float SCALE_ = 0.088388347648318447f;  // 1/sqrt(128)
// ws per (b,kvh,part): O[G][D], m[G], l[G]
constexpr int PSTRIDE_ = G_ * D_ + 2 * G_;       // 520 floats
constexpr size_t CNT_OFF_ = 32u * 1024u * 1024u; // counters at ws+32MB
}

__global__ __launch_bounds__(256) void pa_fused(
    const float* __restrict__ q,        // [B][H][D]
    const float* __restrict__ kc,       // [NUM_SLOTS][KVH][D]
    const float* __restrict__ vc,       // [NUM_SLOTS][KVH][D]
    const int* __restrict__ slots,      // [B][MAX_CTX]
    const int* __restrict__ ctx_lens,   // [B]
    float* __restrict__ ws,
    int* __restrict__ counters,         // [B][2], zeroed per call
    float* __restrict__ out)            // [B][H][D]
{
  const int part = blockIdx.x;
  const int quad = blockIdx.y;           // 0 -> kvh 0..3, 1 -> kvh 4..7
  const int b    = blockIdx.z;
  const int ctx  = ctx_lens[b];
  const int t0   = part * PART_;
  if (t0 >= ctx) return;                 // uniform early-exit, not counted
  const int t1 = min(t0 + PART_, ctx);
  const int np = min(NPART_, (ctx + PART_ - 1) / PART_);

  const int tid  = threadIdx.x;
  const int wv   = tid >> 6;             // wave 0..3
  const int lane = tid & 63;
  const int grp  = lane >> 4;            // 0..3 -> kvh = quad*4+grp
  const int sub  = lane & 15;            // owns dims [8*sub, 8*sub+8)
  const int kvh  = quad * 4 + grp;

  // Q fragments for this group's kvh (4 heads x 8 dims), pre-scaled
  float4 qa[G_], qb[G_];
#pragma unroll
  for (int g = 0; g < G_; ++g) {
    const float* qp = q + ((size_t)b * H_ + (size_t)(kvh * G_ + g)) * D_ + 8 * sub;
    qa[g] = *(const float4*)qp;
    qb[g] = *(const float4*)(qp + 4);
    qa[g].x *= SCALE_; qa[g].y *= SCALE_; qa[g].z *= SCALE_; qa[g].w *= SCALE_;
    qb[g].x *= SCALE_; qb[g].y *= SCALE_; qb[g].z *= SCALE_; qb[g].w *= SCALE_;
  }

  float m[G_], l[G_];
  float4 aa[G_], ab[G_];
#pragma unroll
  for (int g = 0; g < G_; ++g) {
    m[g] = -INFINITY;
    l[g] = 0.f;
    aa[g] = make_float4(0.f, 0.f, 0.f, 0.f);
    ab[g] = make_float4(0.f, 0.f, 0.f, 0.f);
  }

  const int* sp = slots + (size_t)b * MAX_CTX_;
  const int tmax = t1 - 1;
  const int loff = kvh * D_ + 8 * sub;   // contiguous 2KB per quad

  int slot_nxt = sp[min(t0 + 4 + wv, tmax)];
  {
    const int slot_cur = sp[min(t0 + wv, tmax)];
    const size_t roff = (size_t)slot_cur * (KVH_ * D_) + loff;
    // current K/V held in k0..v1 below
    float4 k0 = *(const float4*)(kc + roff);
    float4 k1 = *(const float4*)(kc + roff + 4);
    float4 v0 = *(const float4*)(vc + roff);
    float4 v1 = *(const float4*)(vc + roff + 4);

    for (int base = t0; base < t1; base += 4) {
      const int slot_n2 = sp[min(base + 8 + wv, tmax)];
      const size_t noff = (size_t)slot_nxt * (KVH_ * D_) + loff;
      const float4 nk0 = *(const float4*)(kc + noff);
      const float4 nk1 = *(const float4*)(kc + noff + 4);
      const float4 nv0 = *(const float4*)(vc + noff);
      const float4 nv1 = *(const float4*)(vc + noff + 4);

      const int t = base + wv;
      if (t < t1) {
        float s[G_];
#pragma unroll
        for (int g = 0; g < G_; ++g) {
          s[g] = qa[g].x * k0.x + qa[g].y * k0.y + qa[g].z * k0.z + qa[g].w * k0.w
               + qb[g].x * k1.x + qb[g].y * k1.y + qb[g].z * k1.z + qb[g].w * k1.w;
        }
#pragma unroll
        for (int g = 0; g < G_; ++g) {
#pragma unroll
          for (int o = 1; o < 16; o <<= 1) s[g] += __shfl_xor(s[g], o, 64);
        }
        const bool need = (s[0] > m[0] + 8.f) | (s[1] > m[1] + 8.f) |
                          (s[2] > m[2] + 8.f) | (s[3] > m[3] + 8.f);
        if (need) {
#pragma unroll
          for (int g = 0; g < G_; ++g) {
            const float mn = fmaxf(m[g], s[g]);
            const float c = __expf(m[g] - mn);   // first token: exp(-inf)=0
            m[g] = mn; l[g] *= c;
            aa[g].x *= c; aa[g].y *= c; aa[g].z *= c; aa[g].w *= c;
            ab[g].x *= c; ab[g].y *= c; ab[g].z *= c; ab[g].w *= c;
          }
        }
#pragma unroll
        for (int g = 0; g < G_; ++g) {
          const float p = __expf(s[g] - m[g]);   // bounded by e^8
          l[g] += p;
          aa[g].x += p * v0.x; aa[g].y += p * v0.y;
          aa[g].z += p * v0.z; aa[g].w += p * v0.w;
          ab[g].x += p * v1.x; ab[g].y += p * v1.y;
          ab[g].z += p * v1.z; ab[g].w += p * v1.w;
        }
      }
      k0 = nk0; k1 = nk1; v0 = nv0; v1 = nv1;
      slot_nxt = slot_n2;
    }
  }

  // ---- cross-wave merge per (grp=kvh, g) via LDS ----
  __shared__ float sm_[4][4][G_];          // [wave][grp][g]
  __shared__ float sl_[4][4][G_];
  __shared__ float sa_[4][4][G_][16][8];   // 32 KB
#pragma unroll
  for (int g = 0; g < G_; ++g) {
    *(float4*)&sa_[wv][grp][g][sub][0] = aa[g];
    *(float4*)&sa_[wv][grp][g][sub][4] = ab[g];
  }
  if (sub == 0) {
#pragma unroll
    for (int g = 0; g < G_; ++g) { sm_[wv][grp][g] = m[g]; sl_[wv][grp][g] = l[g]; }
  }
  __syncthreads();

  // wave wv finalizes kvh_out = quad*4 + wv; lane handles head gg=grp
  {
    const int gg = grp;
    const float M = fmaxf(fmaxf(sm_[0][wv][gg], sm_[1][wv][gg]),
                          fmaxf(sm_[2][wv][gg], sm_[3][wv][gg]));  // finite
    float L = 0.f;
    float4 Oa = make_float4(0.f, 0.f, 0.f, 0.f);
    float4 Ob = make_float4(0.f, 0.f, 0.f, 0.f);
#pragma unroll
    for (int w = 0; w < 4; ++w) {
      const float c = __expf(sm_[w][wv][gg] - M);   // empty wave: exp(-inf)=0
      L += sl_[w][wv][gg] * c;
      const float* ap = &sa_[w][wv][gg][sub][0];
      Oa.x += ap[0] * c; Oa.y += ap[1] * c; Oa.z += ap[2] * c; Oa.w += ap[3] * c;
      Ob.x += ap[4] * c; Ob.y += ap[5] * c; Ob.z += ap[6] * c; Ob.w += ap[7] * c;
    }
    float* wp = ws + (((size_t)b * KVH_ + (quad * 4 + wv)) * NPART_ + part) * PSTRIDE_;
    *(float4*)(wp + gg * D_ + 8 * sub)     = Oa;
    *(float4*)(wp + gg * D_ + 8 * sub + 4) = Ob;
    if (sub == 0) {
      wp[G_ * D_ + gg]      = M;
      wp[G_ * D_ + G_ + gg] = L;
    }
  }

  // ---- completion count; last block per (b,quad) merges all parts ----
  __threadfence();                        // release partial writes (device scope)
  __shared__ int isLast;
  if (tid == 0)
    isLast = (atomicAdd(&counters[b * 2 + quad], 1) == np - 1);
  __syncthreads();
  if (!isLast) return;
  __threadfence();                        // acquire other blocks' partials

  // 4 kvh x G x D = 2048 outputs; 8 per thread
  for (int o = tid; o < 4 * G_ * D_; o += 256) {
    const int kv = quad * 4 + (o >> 9);   // o / 512
    const int g  = (o >> 7) & 3;
    const int d  = o & 127;
    const float* basep = ws + ((size_t)b * KVH_ + kv) * NPART_ * PSTRIDE_;
    float M = -INFINITY;
    for (int p = 0; p < np; ++p)
      M = fmaxf(M, basep[p * PSTRIDE_ + G_ * D_ + g]);
    float L = 0.f, O = 0.f;
    for (int p = 0; p < np; ++p) {
      const float c = __expf(basep[p * PSTRIDE_ + G_ * D_ + g] - M);
      L += basep[p * PSTRIDE_ + G_ * D_ + G_ + g] * c;
      O += basep[p * PSTRIDE_ + g * D_ + d] * c;
    }
    out[((size_t)b * H_ + (size_t)(kv * G_ + g)) * D_ + d] = O / L;
  }
}

extern "C" void kernel_launch(void* const* d_in, const int* in_sizes, int n_in,
                              void* d_out, int out_size, void* d_ws, size_t ws_size,
                              hipStream_t stream) {
  const float* q     = (const float*)d_in[0];
  const float* kc    = (const float*)d_in[1];
  const float* vc    = (const float*)d_in[2];
  const int*   slots = (const int*)d_in[3];
  const int*   lens  = (const int*)d_in[4];
  float* out = (float*)d_out;
  float* ws  = (float*)d_ws;                       // partials: ~17.3 MB
  int*   cnt = (int*)((char*)d_ws + CNT_OFF_);     // 32 counters at +32MB

  hipMemsetAsync(cnt, 0, B_ * 2 * sizeof(int), stream);
  dim3 grid(NPART_, KVH_ / 4, B_);                 // 64 x 2 x 16 = 2048
  pa_fused<<<grid, 256, 0, stream>>>(q, kc, vc, slots, lens, ws, cnt, out);
}

// Round 8
// 71.214 us; speedup vs baseline: 5.9976x; 5.9976x over previous
//
#include <hip/hip_runtime.h>
#include <hip/hip_bf16.h>

// Paged attention decode, GQA G=4, fp32. Flash-decoding split-K.
// B=16, H=32, KVH=8, D=128, MAX_CTX=4096.
// Layout: 16 lanes per token (lane owns 8 contiguous dims), 4 tokens in
// flight per wave, 4 waves per block, PART=256 tokens per block.
// [R8: rollback to the measured-best R2 artifact, 71.66 us. Fusion (R7)
//  regressed 5.8x: agent-scope fences -> per-XCD L2 wb/inv storms.]

namespace {
constexpr int B_ = 16;
constexpr int H_ = 32;
constexpr int KVH_ = 8;
constexpr int D_ = 128;
constexpr int G_ = H_ / KVH_;            // 4
constexpr int MAX_CTX_ = 4096;
constexpr int PART_ = 256;
constexpr int NPART_ = MAX_CTX_ / PART_; // 16
constexpr float SCALE_ = 0.088388347648318447f;  // 1/sqrt(128)
// ws per (b,kvh,part): O[G][D], m[G], l[G]
constexpr int PSTRIDE_ = G_ * D_ + 2 * G_;       // 520 floats
}

__global__ __launch_bounds__(256) void pa_partial(
    const float* __restrict__ q,        // [B][H][D]
    const float* __restrict__ kc,       // [NUM_SLOTS][KVH][D]
    const float* __restrict__ vc,       // [NUM_SLOTS][KVH][D]
    const int* __restrict__ slots,      // [B][MAX_CTX]
    const int* __restrict__ ctx_lens,   // [B]
    float* __restrict__ ws)
{
  const int part = blockIdx.x;
  const int kvh  = blockIdx.y;
  const int b    = blockIdx.z;
  const int ctx  = ctx_lens[b];
  const int t0   = part * PART_;
  if (t0 >= ctx) return;                 // uniform early-exit
  const int t1 = min(t0 + PART_, ctx);

  const int tid  = threadIdx.x;
  const int wid  = tid >> 6;             // 0..3
  const int lane = tid & 63;
  const int grp  = lane >> 4;            // 0..3 token slot within wave
  const int sub  = lane & 15;            // owns dims [8*sub, 8*sub+8)

  // Q fragments (8 dims per lane, 4 group heads)
  float4 qa[G_], qb[G_];
#pragma unroll
  for (int g = 0; g < G_; ++g) {
    const float* qp = q + ((size_t)b * H_ + (size_t)(kvh * G_ + g)) * D_ + 8 * sub;
    qa[g] = *(const float4*)qp;
    qb[g] = *(const float4*)(qp + 4);
  }

  float m[G_], l[G_];
  float4 aa[G_], ab[G_];
#pragma unroll
  for (int g = 0; g < G_; ++g) {
    m[g] = -INFINITY;
    l[g] = 0.f;
    aa[g] = make_float4(0.f, 0.f, 0.f, 0.f);
    ab[g] = make_float4(0.f, 0.f, 0.f, 0.f);
  }

  const int* sp = slots + (size_t)b * MAX_CTX_;
  const int tmax = t1 - 1;

  // token for this (wave, grp): base + wid*4 + grp; loads clamped to tmax
  int t_cur = t0 + wid * 4 + grp;
  int slot_cur = sp[min(t_cur, tmax)];
  int slot_nxt = sp[min(t_cur + 16, tmax)];

  size_t roff = ((size_t)slot_cur * KVH_ + kvh) * D_ + 8 * sub;
  float4 k0 = *(const float4*)(kc + roff);
  float4 k1 = *(const float4*)(kc + roff + 4);
  float4 v0 = *(const float4*)(vc + roff);
  float4 v1 = *(const float4*)(vc + roff + 4);

  for (int base = t0; base < t1; base += 16) {
    // prefetch slot 2 iterations ahead, K/V 1 iteration ahead
    const int slot_n2 = sp[min(base + 32 + wid * 4 + grp, tmax)];
    const size_t noff = ((size_t)slot_nxt * KVH_ + kvh) * D_ + 8 * sub;
    const float4 nk0 = *(const float4*)(kc + noff);
    const float4 nk1 = *(const float4*)(kc + noff + 4);
    const float4 nv0 = *(const float4*)(vc + noff);
    const float4 nv1 = *(const float4*)(vc + noff + 4);

    const int t = base + wid * 4 + grp;
    if (t < t1) {
      float s[G_];
#pragma unroll
      for (int g = 0; g < G_; ++g) {
        s[g] = qa[g].x * k0.x + qa[g].y * k0.y + qa[g].z * k0.z + qa[g].w * k0.w
             + qb[g].x * k1.x + qb[g].y * k1.y + qb[g].z * k1.z + qb[g].w * k1.w;
      }
      // reduce across the 16-lane group (xor<16 stays within group)
#pragma unroll
      for (int g = 0; g < G_; ++g) {
#pragma unroll
        for (int o = 1; o < 16; o <<= 1) s[g] += __shfl_xor(s[g], o, 64);
        s[g] *= SCALE_;
      }
      // defer-max: rescale only when a score exceeds m+8 (rare)
      const bool need = (s[0] > m[0] + 8.f) | (s[1] > m[1] + 8.f) |
                        (s[2] > m[2] + 8.f) | (s[3] > m[3] + 8.f);
      if (need) {
#pragma unroll
        for (int g = 0; g < G_; ++g) {
          const float mn = fmaxf(m[g], s[g]);
          const float c = __expf(m[g] - mn);   // first token: exp(-inf)=0
          m[g] = mn; l[g] *= c;
          aa[g].x *= c; aa[g].y *= c; aa[g].z *= c; aa[g].w *= c;
          ab[g].x *= c; ab[g].y *= c; ab[g].z *= c; ab[g].w *= c;
        }
      }
#pragma unroll
      for (int g = 0; g < G_; ++g) {
        const float p = __expf(s[g] - m[g]);   // bounded by e^8
        l[g] += p;
        aa[g].x += p * v0.x; aa[g].y += p * v0.y;
        aa[g].z += p * v0.z; aa[g].w += p * v0.w;
        ab[g].x += p * v1.x; ab[g].y += p * v1.y;
        ab[g].z += p * v1.z; ab[g].w += p * v1.w;
      }
    }
    k0 = nk0; k1 = nk1; v0 = nv0; v1 = nv1;
    slot_nxt = slot_n2;
  }

  // ---- combine the wave's 4 lane-groups via shfl (dims align lane-wise) ----
#pragma unroll
  for (int o = 16; o <= 32; o <<= 1) {
#pragma unroll
    for (int g = 0; g < G_; ++g) {
      const float mo = __shfl_xor(m[g], o, 64);
      const float lo = __shfl_xor(l[g], o, 64);
      float4 ao, bo;
      ao.x = __shfl_xor(aa[g].x, o, 64); ao.y = __shfl_xor(aa[g].y, o, 64);
      ao.z = __shfl_xor(aa[g].z, o, 64); ao.w = __shfl_xor(aa[g].w, o, 64);
      bo.x = __shfl_xor(ab[g].x, o, 64); bo.y = __shfl_xor(ab[g].y, o, 64);
      bo.z = __shfl_xor(ab[g].z, o, 64); bo.w = __shfl_xor(ab[g].w, o, 64);
      const float M = fmaxf(m[g], mo);
      const bool dead = (M == -INFINITY);        // both groups empty
      const float c1 = dead ? 0.f : __expf(m[g] - M);
      const float c2 = dead ? 0.f : __expf(mo - M);
      l[g] = l[g] * c1 + lo * c2;
      aa[g].x = aa[g].x * c1 + ao.x * c2; aa[g].y = aa[g].y * c1 + ao.y * c2;
      aa[g].z = aa[g].z * c1 + ao.z * c2; aa[g].w = aa[g].w * c1 + ao.w * c2;
      ab[g].x = ab[g].x * c1 + bo.x * c2; ab[g].y = ab[g].y * c1 + bo.y * c2;
      ab[g].z = ab[g].z * c1 + bo.z * c2; ab[g].w = ab[g].w * c1 + bo.w * c2;
      m[g] = M;
    }
  }

  // ---- combine 4 waves via LDS ----
  __shared__ float sm_[4][G_];
  __shared__ float sl_[4][G_];
  __shared__ float sa_[4][G_][16][8];   // 8 KB
  if (grp == 0) {
#pragma unroll
    for (int g = 0; g < G_; ++g) {
      *(float4*)&sa_[wid][g][sub][0] = aa[g];
      *(float4*)&sa_[wid][g][sub][4] = ab[g];
    }
    if (sub == 0) {
#pragma unroll
      for (int g = 0; g < G_; ++g) { sm_[wid][g] = m[g]; sl_[wid][g] = l[g]; }
    }
  }
  __syncthreads();

  // wave wid finalizes head g=wid; lane covers dims 2*lane, 2*lane+1
  const int g = wid;
  const float M = fmaxf(fmaxf(sm_[0][g], sm_[1][g]),
                        fmaxf(sm_[2][g], sm_[3][g]));   // finite: block has >=1 token
  const int si = lane >> 2;
  const int sj = (2 * lane) & 7;
  float L = 0.f, Ox = 0.f, Oy = 0.f;
#pragma unroll
  for (int w = 0; w < 4; ++w) {
    const float c = __expf(sm_[w][g] - M);   // empty wave: exp(-inf)=0
    L += sl_[w][g] * c;
    Ox += sa_[w][g][si][sj] * c;
    Oy += sa_[w][g][si][sj + 1] * c;
  }
  float* wp = ws + (((size_t)b * KVH_ + kvh) * NPART_ + part) * PSTRIDE_;
  *(float2*)(wp + g * D_ + 2 * lane) = make_float2(Ox, Oy);
  if (lane == 0) {
    wp[G_ * D_ + g] = M;
    wp[G_ * D_ + G_ + g] = L;
  }
}

__global__ __launch_bounds__(512) void pa_reduce(
    const float* __restrict__ ws,
    const int* __restrict__ ctx_lens,
    float* __restrict__ out)
{
  const int bk = blockIdx.x;
  const int b = bk / KVH_;
  const int kvh = bk % KVH_;
  const int g = threadIdx.x >> 7;     // 0..3
  const int d = threadIdx.x & 127;    // 0..127
  const int ctx = ctx_lens[b];
  int np = (ctx + PART_ - 1) / PART_;
  if (np > NPART_) np = NPART_;

  const float* base = ws + ((size_t)b * KVH_ + kvh) * NPART_ * PSTRIDE_;

  float M = -INFINITY;
  for (int p = 0; p < np; ++p)
    M = fmaxf(M, base[p * PSTRIDE_ + G_ * D_ + g]);

  float L = 0.f, O = 0.f;
  for (int p = 0; p < np; ++p) {
    const float mp = base[p * PSTRIDE_ + G_ * D_ + g];
    const float lp = base[p * PSTRIDE_ + G_ * D_ + G_ + g];
    const float c = __expf(mp - M);
    L += lp * c;
    O += base[p * PSTRIDE_ + g * D_ + d] * c;
  }
  out[((size_t)b * H_ + (size_t)(kvh * G_ + g)) * D_ + d] = O / L;
}

extern "C" void kernel_launch(void* const* d_in, const int* in_sizes, int n_in,
                              void* d_out, int out_size, void* d_ws, size_t ws_size,
                              hipStream_t stream) {
  const float* q     = (const float*)d_in[0];
  const float* kc    = (const float*)d_in[1];
  const float* vc    = (const float*)d_in[2];
  const int*   slots = (const int*)d_in[3];
  const int*   lens  = (const int*)d_in[4];
  float* out = (float*)d_out;
  float* ws  = (float*)d_ws;   // needs 16*8*16*520*4 B ~= 4.3 MB

  dim3 grid1(NPART_, KVH_, B_);
  pa_partial<<<grid1, 256, 0, stream>>>(q, kc, vc, slots, lens, ws);
  pa_reduce<<<B_ * KVH_, 512, 0, stream>>>(ws, lens, out);
}